// Round 6
// baseline (3377.069 us; speedup 1.0000x reference)
//
#include <hip/hip_runtime.h>
#include <hip/hip_cooperative_groups.h>

// RNN_73701638799445: 2-layer tanh RNN.
// v5: v4's persistent recurrence with grid.sync() replaced by a lightweight
//     hand-rolled grid barrier (agent-scope release fence -> one atomicAdd per
//     block -> tight spin with s_sleep(2) -> acquire fence). v3/v4 showed
//     grid.sync() costs ~25-30us/phase (sleep-quantized spin + seq-cst fences);
//     phase work itself is ~3-5us. Dataflow identical to v4 (verified correct).
// Decoder/U0 GEMM unchanged (XCD n-band swizzle; decoder FETCH 360->88MB verified).

#define S_LEN 64
#define BATCH 64
#define HID   1024
#define VOCAB 10000
#define VPAD  10240           // 80 * 128
#define SB    4096            // S_LEN * BATCH
#define SBV   40960000        // SB * VOCAB
#define NBLK  192

typedef __attribute__((ext_vector_type(4))) float  f32x4;
typedef __attribute__((ext_vector_type(8))) __bf16 bf16x8;

__device__ inline unsigned short f2bf(float x) {
  union { float f; unsigned int u; } v; v.f = x;
  unsigned int r = v.u + 0x7fffu + ((v.u >> 16) & 1u);   // RNE
  return (unsigned short)(r >> 16);
}
__device__ inline float bf2f(unsigned short s) {
  union { unsigned int u; float f; } v; v.u = ((unsigned int)s) << 16;
  return v.f;
}

// ---------------- prep kernels ----------------

__global__ __launch_bounds__(256) void prep_x(
    const int* __restrict__ inputs, const float* __restrict__ emb,
    unsigned short* __restrict__ Xbf) {
  int i = blockIdx.x * 256 + threadIdx.x;       // SB*HID/4 threads
  int row = i >> 8;
  int c4  = (i & 255) * 4;
  int tok = inputs[row];
  const float4 v = *reinterpret_cast<const float4*>(emb + (size_t)tok * HID + c4);
  unsigned short* o = Xbf + (size_t)row * HID + c4;
  o[0] = f2bf(v.x); o[1] = f2bf(v.y); o[2] = f2bf(v.z); o[3] = f2bf(v.w);
}

// W0 -> bf16; Wh0 -> B0c [hi|lo] (row 2048); W1 -> B1a [hi|lo]; Wh1 -> B1b [hi|lo]
__global__ __launch_bounds__(256) void prep_w(
    const float* __restrict__ W0, const float* __restrict__ Wh0,
    const float* __restrict__ W1, const float* __restrict__ Wh1,
    unsigned short* __restrict__ W0bf, unsigned short* __restrict__ B0c,
    unsigned short* __restrict__ B1a, unsigned short* __restrict__ B1b) {
  int id = blockIdx.x * 256 + threadIdx.x;      // HID*HID threads
  W0bf[id] = f2bf(W0[id]);
  size_t base = (size_t)(id >> 10) * 2048 + (id & 1023);
  {
    float w = Wh0[id];
    unsigned short hi = f2bf(w);
    B0c[base] = hi; B0c[base + 1024] = f2bf(w - bf2f(hi));
  }
  {
    float w = W1[id];
    unsigned short hi = f2bf(w);
    B1a[base] = hi; B1a[base + 1024] = f2bf(w - bf2f(hi));
  }
  {
    float w = Wh1[id];
    unsigned short hi = f2bf(w);
    B1b[base] = hi; B1b[base + 1024] = f2bf(w - bf2f(hi));
  }
}

__global__ __launch_bounds__(256) void prep_wd(
    const float* __restrict__ Wd, const float* __restrict__ bd,
    unsigned short* __restrict__ Wdbf, float* __restrict__ bdp) {
  int id = blockIdx.x * 256 + threadIdx.x;      // VPAD*1024 threads
  int row = id >> 10;
  Wdbf[id] = (row < VOCAB) ? f2bf(Wd[id]) : (unsigned short)0;
  if (id < VPAD) bdp[id] = (id < VOCAB) ? bd[id] : 0.0f;
}

// init state buffers + zero the grid-barrier counter
__global__ __launch_bounds__(256) void prep_h(
    const float* __restrict__ hidden,
    unsigned short* __restrict__ A0x, unsigned short* __restrict__ A1x,
    unsigned int* __restrict__ barcnt) {
  int id = blockIdx.x * 256 + threadIdx.x;      // BATCH*HID threads
  if (id == 0) *barcnt = 0u;
  int b = id >> 10, n = id & 1023;
  float h0 = hidden[id];
  float h1 = hidden[BATCH * HID + id];
  unsigned short h0hi = f2bf(h0), h1hi = f2bf(h1);
  size_t o = (size_t)b * 2048 + n;
  A0x[o] = h0hi; A0x[o + 1024] = f2bf(h0 - bf2f(h0hi));
  A1x[o] = h1hi; A1x[o + 1024] = f2bf(h1 - bf2f(h1hi));
}

// ---------------- big bf16 GEMM (unchanged) ----------------
__global__ __launch_bounds__(256) void gemm_bt_bias(
    const unsigned short* __restrict__ A, const unsigned short* __restrict__ B,
    const float* __restrict__ bias, float* __restrict__ C,
    int K, int N, int ldc) {
  unsigned bx = blockIdx.x, by = blockIdx.y;
  if ((gridDim.x & 7u) == 0u) {
    const unsigned lin = blockIdx.x + gridDim.x * blockIdx.y;
    const unsigned xpx = gridDim.x >> 3;
    const unsigned xcd = lin & 7u;
    const unsigned idx = lin >> 3;
    bx = xcd * xpx + idx % xpx;
    by = idx / xpx;
  }
  const int m0 = by * 128;
  const int n0 = bx * 128;
  __shared__ __align__(16) unsigned short As[128 * 64];
  __shared__ __align__(16) unsigned short Bs[128 * 64];
  const int tid = threadIdx.x;
  const int lane = tid & 63, w = tid >> 6;
  const int wm = w >> 1, wn = w & 1;
  f32x4 acc[4][4] = {};
  for (int k0 = 0; k0 < K; k0 += 64) {
#pragma unroll
    for (int i = 0; i < 4; ++i) {
      int off = i * 256 + tid;
      int row = off >> 3;
      int c8  = off & 7;
      __builtin_amdgcn_global_load_lds(
          (const __attribute__((address_space(1))) unsigned int*)(const void*)
              (A + (size_t)(m0 + row) * K + k0 + c8 * 8),
          (__attribute__((address_space(3))) unsigned int*)(void*)(As + (size_t)off * 8),
          16, 0, 0);
      __builtin_amdgcn_global_load_lds(
          (const __attribute__((address_space(1))) unsigned int*)(const void*)
              (B + (size_t)(n0 + row) * K + k0 + c8 * 8),
          (__attribute__((address_space(3))) unsigned int*)(void*)(Bs + (size_t)off * 8),
          16, 0, 0);
    }
    __syncthreads();
#pragma unroll
    for (int kk = 0; kk < 64; kk += 32) {
      bf16x8 af[4], bfr[4];
#pragma unroll
      for (int f = 0; f < 4; ++f) {
        int ar = wm * 64 + f * 16 + (lane & 15);
        int ac = kk + (lane >> 4) * 8;
        af[f]  = *reinterpret_cast<const bf16x8*>(&As[ar * 64 + ac]);
        int br = wn * 64 + f * 16 + (lane & 15);
        bfr[f] = *reinterpret_cast<const bf16x8*>(&Bs[br * 64 + ac]);
      }
#pragma unroll
      for (int i = 0; i < 4; ++i)
#pragma unroll
        for (int j = 0; j < 4; ++j)
          acc[i][j] = __builtin_amdgcn_mfma_f32_16x16x32_bf16(af[i], bfr[j], acc[i][j], 0, 0, 0);
    }
    __syncthreads();
  }
  const int rbase = (lane >> 4) * 4;
  const int cbase = lane & 15;
#pragma unroll
  for (int i = 0; i < 4; ++i) {
#pragma unroll
    for (int j = 0; j < 4; ++j) {
      int col = n0 + wn * 64 + j * 16 + cbase;
      if (col < N) {
        float bv = bias[col];
#pragma unroll
        for (int r = 0; r < 4; ++r) {
          int row = m0 + wm * 64 + i * 16 + rbase + r;
          C[(size_t)row * ldc + col] = acc[i][j][r] + bv;
        }
      }
    }
  }
}

// ---------------- persistent recurrence kernel ----------------
// 192 blocks x 512 thr. type=bid>>6: 0=L0, 1=L1a, 2=L1b; nt=bid&63 -> 16 n-cols.
// Wave w: m-tile (w&3), k-half (w>>2). Unique-k 1024 in 8 chunks of 128.
// Stage chunk: [64 rows][hi 128 | lo 128 shorts] = 32KB, double-buffered.
// Grid barrier: custom (release fence -> atomicAdd -> tight spin -> acquire fence).
__global__ __launch_bounds__(512, 1) void rnn_persist(
    const unsigned short* __restrict__ B0c,
    const unsigned short* __restrict__ B1a,
    const unsigned short* __restrict__ B1b,
    const float* __restrict__ U0,
    const float* __restrict__ b1,
    unsigned short* __restrict__ A0x, unsigned short* __restrict__ A0y,
    unsigned short* __restrict__ A1x, unsigned short* __restrict__ A1y,
    float* __restrict__ P0, float* __restrict__ P1,
    unsigned short* __restrict__ H1bf,
    float* __restrict__ hid0, float* __restrict__ hid1,
    unsigned int* barcnt) {
  __shared__ __align__(16) unsigned short Wlds[16 * 2048];   // 64 KB
  __shared__ __align__(16) unsigned short Ast[2][64 * 256];  // 2 x 32 KB
  float* red = reinterpret_cast<float*>(&Ast[0][0]);         // 8 KB overlay

  const int bid  = blockIdx.x;
  const int type = bid >> 6;
  const int nt   = bid & 63;
  const int n0   = nt << 4;
  const int tid  = threadIdx.x, lane = tid & 63, w = tid >> 6;
  const int mt = w & 3, kh = w >> 2;

  // weight slice preload (16 rows x 2048 shorts, chunk-XOR swizzled)
  const unsigned short* Wsrc = (type == 0) ? B0c : (type == 1) ? B1a : B1b;
  for (int c = tid; c < 4096; c += 512) {
    int row = c >> 8, cc = c & 255;
    bf16x8 v = *reinterpret_cast<const bf16x8*>(Wsrc + (size_t)(n0 + row) * 2048 + cc * 8);
    *reinterpret_cast<bf16x8*>(&Wlds[row * 2048 + (cc ^ (row & 7)) * 8]) = v;
  }
  __syncthreads();

  const int brow = lane & 15;
  const int arow = mt * 16 + brow;
  const int asw  = arow & 7;
  const int bsw  = brow & 7;
  const int kgrp = lane >> 4;                 // 0..3
  // epilogue geometry: thread -> (batch row em, 2 cols cl, cl+1)
  const int em  = tid >> 3;
  const int cl  = (tid & 7) * 2;
  const int emt = em >> 4, eml = em & 15;

  for (int p = 0; p < 66; ++p) {
    const int pm = p & 1;
    const bool active = (type == 0) ? (p < 64)
                      : (type == 1) ? (p >= 1 && p < 65)
                      : (p >= 2);
    if (active) {
      const unsigned short* Aprev = (type == 2) ? (pm ? A1y : A1x) : (pm ? A0y : A0x);

      // epilogue operand prefetch (retires before staging drains; rides vmcnt FIFO)
      float2 preA = make_float2(0.f, 0.f), preB = make_float2(0.f, 0.f);
      if (type == 0) {
        preA = *reinterpret_cast<const float2*>(U0 + (size_t)p * (BATCH * HID) + em * HID + n0 + cl);
      } else if (type == 2) {
        const float* Pp = pm ? P1 : P0;
        preA = *reinterpret_cast<const float2*>(Pp + (size_t)em * HID + n0 + cl);
        preB = *reinterpret_cast<const float2*>(b1 + n0 + cl);
      }

      // stage chunk c into buffer b: LDS linear dest, inverse-swizzled global src
      auto STAGE = [&](int c, int b) {
#pragma unroll
        for (int t = 0; t < 4; ++t) {
          int id  = tid + t * 512;                     // 0..2047
          int row = id >> 5, ci = id & 31;
          int col = ((ci & 15) ^ (row & 7)) * 8 + c * 128 + ((ci >> 4) << 10);
          __builtin_amdgcn_global_load_lds(
              (const __attribute__((address_space(1))) unsigned int*)(const void*)
                  (Aprev + (size_t)row * 2048 + col),
              (__attribute__((address_space(3))) unsigned int*)(void*)(&Ast[b][id * 8]),
              16, 0, 0);
        }
      };

      STAGE(0, 0);
      STAGE(1, 1);
      f32x4 acc0 = {0.f, 0.f, 0.f, 0.f};
      f32x4 acc1 = {0.f, 0.f, 0.f, 0.f};
#pragma unroll
      for (int c = 0; c < 8; ++c) {
        if (c < 7) { asm volatile("s_waitcnt vmcnt(4)" ::: "memory"); }
        else       { asm volatile("s_waitcnt vmcnt(0)" ::: "memory"); }
        __builtin_amdgcn_sched_barrier(0);
        __builtin_amdgcn_s_barrier();
        __builtin_amdgcn_sched_barrier(0);
        const unsigned short* Ab = &Ast[c & 1][0];
        {
          int col8 = kh * 8 + kgrp;                       // kc = 0
          int ch   = ((c * 128 + kh * 64 + kgrp * 8) >> 3) ^ bsw;
          const unsigned short* ap = Ab + arow * 256 + (col8 ^ asw) * 8;
          const unsigned short* bp = Wlds + brow * 2048 + ch * 8;
          bf16x8 ah = *reinterpret_cast<const bf16x8*>(ap);
          bf16x8 al = *reinterpret_cast<const bf16x8*>(ap + 128);
          bf16x8 bh = *reinterpret_cast<const bf16x8*>(bp);
          bf16x8 bl = *reinterpret_cast<const bf16x8*>(bp + 1024);
          acc0 = __builtin_amdgcn_mfma_f32_16x16x32_bf16(ah, bh, acc0, 0, 0, 0);
          acc0 = __builtin_amdgcn_mfma_f32_16x16x32_bf16(ah, bl, acc0, 0, 0, 0);
          acc0 = __builtin_amdgcn_mfma_f32_16x16x32_bf16(al, bh, acc0, 0, 0, 0);
        }
        {
          int col8 = kh * 8 + 4 + kgrp;                   // kc = 1
          int ch   = ((c * 128 + kh * 64 + 32 + kgrp * 8) >> 3) ^ bsw;
          const unsigned short* ap = Ab + arow * 256 + (col8 ^ asw) * 8;
          const unsigned short* bp = Wlds + brow * 2048 + ch * 8;
          bf16x8 ah = *reinterpret_cast<const bf16x8*>(ap);
          bf16x8 al = *reinterpret_cast<const bf16x8*>(ap + 128);
          bf16x8 bh = *reinterpret_cast<const bf16x8*>(bp);
          bf16x8 bl = *reinterpret_cast<const bf16x8*>(bp + 1024);
          acc1 = __builtin_amdgcn_mfma_f32_16x16x32_bf16(ah, bh, acc1, 0, 0, 0);
          acc1 = __builtin_amdgcn_mfma_f32_16x16x32_bf16(ah, bl, acc1, 0, 0, 0);
          acc1 = __builtin_amdgcn_mfma_f32_16x16x32_bf16(al, bh, acc1, 0, 0, 0);
        }
        asm volatile("s_waitcnt lgkmcnt(0)" ::: "memory");
        __builtin_amdgcn_sched_barrier(0);
        __builtin_amdgcn_s_barrier();
        __builtin_amdgcn_sched_barrier(0);
        if (c < 6) STAGE(c + 2, c & 1);
      }

      // cross-(k-half) reduction: wave w dumps its 16x16 tile
      {
        const int rr = (lane >> 4) * 4;
#pragma unroll
        for (int r = 0; r < 4; ++r)
          red[w * 256 + (rr + r) * 16 + brow] = acc0[r] + acc1[r];
      }
      __syncthreads();
      {
        int base = emt * 256 + eml * 16 + cl;
        float v0 = red[base]     + red[base + 1024];
        float v1 = red[base + 1] + red[base + 1025];
        if (type == 0) {
          float h0v = tanhf(v0 + preA.x), h1v = tanhf(v1 + preA.y);
          unsigned short* An = pm ? A0x : A0y;
          ushort2 hv, lv;
          hv.x = f2bf(h0v); lv.x = f2bf(h0v - bf2f(hv.x));
          hv.y = f2bf(h1v); lv.y = f2bf(h1v - bf2f(hv.y));
          *reinterpret_cast<ushort2*>(&An[(size_t)em * 2048 + n0 + cl])        = hv;
          *reinterpret_cast<ushort2*>(&An[(size_t)em * 2048 + 1024 + n0 + cl]) = lv;
          if (p == S_LEN - 1) {
            float2 f; f.x = h0v; f.y = h1v;
            *reinterpret_cast<float2*>(&hid0[(size_t)em * HID + n0 + cl]) = f;
          }
        } else if (type == 1) {
          float* Pn = pm ? P0 : P1;
          float2 f; f.x = v0; f.y = v1;
          *reinterpret_cast<float2*>(&Pn[(size_t)em * HID + n0 + cl]) = f;
        } else {
          float h0v = tanhf(v0 + preA.x + preB.x), h1v = tanhf(v1 + preA.y + preB.y);
          unsigned short* An = pm ? A1x : A1y;
          ushort2 hv, lv;
          hv.x = f2bf(h0v); lv.x = f2bf(h0v - bf2f(hv.x));
          hv.y = f2bf(h1v); lv.y = f2bf(h1v - bf2f(hv.y));
          *reinterpret_cast<ushort2*>(&An[(size_t)em * 2048 + n0 + cl])        = hv;
          *reinterpret_cast<ushort2*>(&An[(size_t)em * 2048 + 1024 + n0 + cl]) = lv;
          unsigned short* H1t = H1bf + (size_t)(p - 2) * (BATCH * HID);
          *reinterpret_cast<ushort2*>(&H1t[(size_t)em * HID + n0 + cl]) = hv;
          if (p == 65) {
            float2 f; f.x = h0v; f.y = h1v;
            *reinterpret_cast<float2*>(&hid1[(size_t)em * HID + n0 + cl]) = f;
          }
        }
      }
    }

    // ---- lightweight grid barrier (replaces grid.sync) ----
    __syncthreads();                                     // block done with phase p
    __builtin_amdgcn_fence(__ATOMIC_RELEASE, "agent");   // drain + WB L2 (cross-XCD vis)
    if (tid == 0) {
      __hip_atomic_fetch_add(barcnt, 1u, __ATOMIC_RELAXED, __HIP_MEMORY_SCOPE_AGENT);
      const unsigned target = (unsigned)NBLK * (unsigned)(p + 1);
      while (__hip_atomic_load(barcnt, __ATOMIC_RELAXED, __HIP_MEMORY_SCOPE_AGENT) < target)
        __builtin_amdgcn_s_sleep(2);
    }
    __syncthreads();                                     // broadcast arrival
    __builtin_amdgcn_fence(__ATOMIC_ACQUIRE, "agent");   // invalidate stale L1/L2
  }
}

// ---------------- launcher ----------------

extern "C" void kernel_launch(void* const* d_in, const int* in_sizes, int n_in,
                              void* d_out, int out_size, void* d_ws, size_t ws_size,
                              hipStream_t stream) {
  (void)in_sizes; (void)n_in; (void)out_size; (void)ws_size;
  const int*   inputs = (const int*)  d_in[0];
  const float* hidden = (const float*)d_in[1];
  const float* emb    = (const float*)d_in[2];
  const float* W0     = (const float*)d_in[3];
  const float* Wh0    = (const float*)d_in[4];
  const float* b0     = (const float*)d_in[5];
  const float* W1     = (const float*)d_in[6];
  const float* Wh1    = (const float*)d_in[7];
  const float* b1     = (const float*)d_in[8];
  const float* Wd     = (const float*)d_in[9];
  const float* bd     = (const float*)d_in[10];

  // scratch inside d_out (consumed before the decoder overwrites logits)
  float*          U0  = (float*)d_out;                                       // 16MB
  unsigned short* Xbf = (unsigned short*)((char*)d_out + (size_t)16777216);  // 8MB

  // persistent scratch in d_ws
  char* ws = (char*)d_ws;
  size_t off = 0;
  auto alloc = [&](size_t bytes) { size_t p = off; off = (off + bytes + 255) & ~(size_t)255; return p; };
  unsigned short* W0bf = (unsigned short*)(ws + alloc((size_t)HID * HID * 2));
  unsigned short* Wdbf = (unsigned short*)(ws + alloc((size_t)VPAD * HID * 2));
  float*          bdp  = (float*)         (ws + alloc((size_t)VPAD * 4));
  unsigned short* B0c  = (unsigned short*)(ws + alloc((size_t)HID * 2048 * 2));
  unsigned short* B1a  = (unsigned short*)(ws + alloc((size_t)HID * 2048 * 2));
  unsigned short* B1b  = (unsigned short*)(ws + alloc((size_t)HID * 2048 * 2));
  unsigned short* H1bf = (unsigned short*)(ws + alloc((size_t)SB * HID * 2));
  unsigned short* A0x  = (unsigned short*)(ws + alloc((size_t)BATCH * 2048 * 2));
  unsigned short* A0y  = (unsigned short*)(ws + alloc((size_t)BATCH * 2048 * 2));
  unsigned short* A1x  = (unsigned short*)(ws + alloc((size_t)BATCH * 2048 * 2));
  unsigned short* A1y  = (unsigned short*)(ws + alloc((size_t)BATCH * 2048 * 2));
  float*          P0   = (float*)         (ws + alloc((size_t)BATCH * HID * 4));
  float*          P1   = (float*)         (ws + alloc((size_t)BATCH * HID * 4));
  unsigned int*   barcnt = (unsigned int*)(ws + alloc(256));

  float* hid0 = (float*)d_out + (size_t)SBV;            // final h0 [B,H]
  float* hid1 = hid0 + (size_t)BATCH * HID;             // final h1 [B,H]

  // prep
  prep_x <<<SB * HID / 4 / 256, 256, 0, stream>>>(inputs, emb, Xbf);
  prep_w <<<HID * HID / 256,    256, 0, stream>>>(W0, Wh0, W1, Wh1, W0bf, B0c, B1a, B1b);
  prep_wd<<<VPAD * HID / 256,   256, 0, stream>>>(Wd, bd, Wdbf, bdp);
  prep_h <<<BATCH * HID / 256,  256, 0, stream>>>(hidden, A0x, A1x, barcnt);

  // U0 = X @ W0^T + b0
  gemm_bt_bias<<<dim3(HID / 128, SB / 128), 256, 0, stream>>>(
      Xbf, W0bf, b0, U0, HID, HID, HID);

  // persistent cooperative recurrence (192 blocks x 512 thr, 128KB static LDS)
  {
    const unsigned short* cB0c = B0c; const unsigned short* cB1a = B1a;
    const unsigned short* cB1b = B1b; const float* cU0 = U0; const float* cb1 = b1;
    void* args[] = {
        (void*)&cB0c, (void*)&cB1a, (void*)&cB1b, (void*)&cU0, (void*)&cb1,
        (void*)&A0x, (void*)&A0y, (void*)&A1x, (void*)&A1y,
        (void*)&P0, (void*)&P1, (void*)&H1bf, (void*)&hid0, (void*)&hid1,
        (void*)&barcnt};
    hipLaunchCooperativeKernel(reinterpret_cast<const void*>(&rnn_persist),
                               dim3(NBLK), dim3(512), args, 0, stream);
  }

  // logits = H1 @ Wd^T + bd
  gemm_bt_bias<<<dim3(VPAD / 128, SB / 128), 256, 0, stream>>>(
      H1bf, Wdbf, bdp, (float*)d_out, HID, VOCAB, VOCAB);
}

// Round 7
// 1631.241 us; speedup vs baseline: 2.0702x; 2.0702x over previous
//
#include <hip/hip_runtime.h>
#include <hip/hip_cooperative_groups.h>

// RNN_73701638799445: 2-layer tanh RNN.
// v6: persistent recurrence, FENCE-FREE cross-block communication.
//   Diagnosis v3-v5: agent release/acquire fences (grid.sync internals / explicit)
//   = per-block L2 writeback+invalidate storm ~30us/phase; MfmaUtil ~1%.
//   Fix: all cross-block state (A0/A1/P) moves through the Infinity Cache via
//   relaxed AGENT-scope atomic load/store (sc1, bypasses non-coherent L1/L2) —
//   no fences at all. Sync = per-phase producer counters, polled (s_sleep) by
//   tid0 of each consumer block; producers: vmcnt(0) -> barrier -> fetch_add.
//   96 blocks x 512thr (3 types x 32 n-slices of 32 cols); weights LDS-resident
//   (128KB, XOR-swizzled, loaded once); A-fragments direct-to-register with
//   depth-2 chunk prefetch. Same split-bf16 math / phase windows as v4 (verified).
// Decoder/U0 GEMM unchanged (XCD n-band swizzle; decoder FETCH 360->88MB verified).

#define S_LEN 64
#define BATCH 64
#define HID   1024
#define VOCAB 10000
#define VPAD  10240           // 80 * 128
#define SB    4096            // S_LEN * BATCH
#define SBV   40960000        // SB * VOCAB
#define NBLK  96
#define NBT   32              // blocks per type

typedef __attribute__((ext_vector_type(4))) float  f32x4;
typedef __attribute__((ext_vector_type(8))) __bf16 bf16x8;
typedef unsigned long long u64;

__device__ inline unsigned short f2bf(float x) {
  union { float f; unsigned int u; } v; v.f = x;
  unsigned int r = v.u + 0x7fffu + ((v.u >> 16) & 1u);   // RNE
  return (unsigned short)(r >> 16);
}
__device__ inline float bf2f(unsigned short s) {
  union { unsigned int u; float f; } v; v.u = ((unsigned int)s) << 16;
  return v.f;
}
__device__ inline bf16x8 mk2(u64 a, u64 b) {
  union { u64 q[2]; bf16x8 v; } u; u.q[0] = a; u.q[1] = b; return u.v;
}
// pack 4 floats -> 4 bf16 hi (ret) and 4 bf16 lo (*lo)
__device__ inline u64 pack4(float h0, float h1, float h2, float h3, u64* lo) {
  unsigned short a = f2bf(h0), b = f2bf(h1), c = f2bf(h2), d = f2bf(h3);
  unsigned short e = f2bf(h0 - bf2f(a)), f = f2bf(h1 - bf2f(b));
  unsigned short g = f2bf(h2 - bf2f(c)), h = f2bf(h3 - bf2f(d));
  *lo = (u64)e | ((u64)f << 16) | ((u64)g << 32) | ((u64)h << 48);
  return (u64)a | ((u64)b << 16) | ((u64)c << 32) | ((u64)d << 48);
}

#define AL64(p)    __hip_atomic_load((const u64*)(p), __ATOMIC_RELAXED, __HIP_MEMORY_SCOPE_AGENT)
#define AS64(p, v) __hip_atomic_store((u64*)(p), (v), __ATOMIC_RELAXED, __HIP_MEMORY_SCOPE_AGENT)

// ---------------- prep kernels ----------------

__global__ __launch_bounds__(256) void prep_x(
    const int* __restrict__ inputs, const float* __restrict__ emb,
    unsigned short* __restrict__ Xbf) {
  int i = blockIdx.x * 256 + threadIdx.x;       // SB*HID/4 threads
  int row = i >> 8;
  int c4  = (i & 255) * 4;
  int tok = inputs[row];
  const float4 v = *reinterpret_cast<const float4*>(emb + (size_t)tok * HID + c4);
  unsigned short* o = Xbf + (size_t)row * HID + c4;
  o[0] = f2bf(v.x); o[1] = f2bf(v.y); o[2] = f2bf(v.z); o[3] = f2bf(v.w);
}

// W0 -> bf16; Wh0 -> B0c [hi|lo] (row 2048); W1 -> B1a [hi|lo]; Wh1 -> B1b [hi|lo]
__global__ __launch_bounds__(256) void prep_w(
    const float* __restrict__ W0, const float* __restrict__ Wh0,
    const float* __restrict__ W1, const float* __restrict__ Wh1,
    unsigned short* __restrict__ W0bf, unsigned short* __restrict__ B0c,
    unsigned short* __restrict__ B1a, unsigned short* __restrict__ B1b) {
  int id = blockIdx.x * 256 + threadIdx.x;      // HID*HID threads
  W0bf[id] = f2bf(W0[id]);
  size_t base = (size_t)(id >> 10) * 2048 + (id & 1023);
  {
    float w = Wh0[id];
    unsigned short hi = f2bf(w);
    B0c[base] = hi; B0c[base + 1024] = f2bf(w - bf2f(hi));
  }
  {
    float w = W1[id];
    unsigned short hi = f2bf(w);
    B1a[base] = hi; B1a[base + 1024] = f2bf(w - bf2f(hi));
  }
  {
    float w = Wh1[id];
    unsigned short hi = f2bf(w);
    B1b[base] = hi; B1b[base + 1024] = f2bf(w - bf2f(hi));
  }
}

__global__ __launch_bounds__(256) void prep_wd(
    const float* __restrict__ Wd, const float* __restrict__ bd,
    unsigned short* __restrict__ Wdbf, float* __restrict__ bdp) {
  int id = blockIdx.x * 256 + threadIdx.x;      // VPAD*1024 threads
  int row = id >> 10;
  Wdbf[id] = (row < VOCAB) ? f2bf(Wd[id]) : (unsigned short)0;
  if (id < VPAD) bdp[id] = (id < VOCAB) ? bd[id] : 0.0f;
}

// init state buffers + zero the 3x66 phase counters
__global__ __launch_bounds__(256) void prep_h(
    const float* __restrict__ hidden,
    unsigned short* __restrict__ A0x, unsigned short* __restrict__ A1x,
    unsigned int* __restrict__ cnt) {
  int id = blockIdx.x * 256 + threadIdx.x;      // BATCH*HID threads
  if (id < 198) cnt[id] = 0u;
  int b = id >> 10, n = id & 1023;
  float h0 = hidden[id];
  float h1 = hidden[BATCH * HID + id];
  unsigned short h0hi = f2bf(h0), h1hi = f2bf(h1);
  size_t o = (size_t)b * 2048 + n;
  A0x[o] = h0hi; A0x[o + 1024] = f2bf(h0 - bf2f(h0hi));
  A1x[o] = h1hi; A1x[o + 1024] = f2bf(h1 - bf2f(h1hi));
}

// ---------------- big bf16 GEMM (unchanged) ----------------
__global__ __launch_bounds__(256) void gemm_bt_bias(
    const unsigned short* __restrict__ A, const unsigned short* __restrict__ B,
    const float* __restrict__ bias, float* __restrict__ C,
    int K, int N, int ldc) {
  unsigned bx = blockIdx.x, by = blockIdx.y;
  if ((gridDim.x & 7u) == 0u) {
    const unsigned lin = blockIdx.x + gridDim.x * blockIdx.y;
    const unsigned xpx = gridDim.x >> 3;
    const unsigned xcd = lin & 7u;
    const unsigned idx = lin >> 3;
    bx = xcd * xpx + idx % xpx;
    by = idx / xpx;
  }
  const int m0 = by * 128;
  const int n0 = bx * 128;
  __shared__ __align__(16) unsigned short As[128 * 64];
  __shared__ __align__(16) unsigned short Bs[128 * 64];
  const int tid = threadIdx.x;
  const int lane = tid & 63, w = tid >> 6;
  const int wm = w >> 1, wn = w & 1;
  f32x4 acc[4][4] = {};
  for (int k0 = 0; k0 < K; k0 += 64) {
#pragma unroll
    for (int i = 0; i < 4; ++i) {
      int off = i * 256 + tid;
      int row = off >> 3;
      int c8  = off & 7;
      __builtin_amdgcn_global_load_lds(
          (const __attribute__((address_space(1))) unsigned int*)(const void*)
              (A + (size_t)(m0 + row) * K + k0 + c8 * 8),
          (__attribute__((address_space(3))) unsigned int*)(void*)(As + (size_t)off * 8),
          16, 0, 0);
      __builtin_amdgcn_global_load_lds(
          (const __attribute__((address_space(1))) unsigned int*)(const void*)
              (B + (size_t)(n0 + row) * K + k0 + c8 * 8),
          (__attribute__((address_space(3))) unsigned int*)(void*)(Bs + (size_t)off * 8),
          16, 0, 0);
    }
    __syncthreads();
#pragma unroll
    for (int kk = 0; kk < 64; kk += 32) {
      bf16x8 af[4], bfr[4];
#pragma unroll
      for (int f = 0; f < 4; ++f) {
        int ar = wm * 64 + f * 16 + (lane & 15);
        int ac = kk + (lane >> 4) * 8;
        af[f]  = *reinterpret_cast<const bf16x8*>(&As[ar * 64 + ac]);
        int br = wn * 64 + f * 16 + (lane & 15);
        bfr[f] = *reinterpret_cast<const bf16x8*>(&Bs[br * 64 + ac]);
      }
#pragma unroll
      for (int i = 0; i < 4; ++i)
#pragma unroll
        for (int j = 0; j < 4; ++j)
          acc[i][j] = __builtin_amdgcn_mfma_f32_16x16x32_bf16(af[i], bfr[j], acc[i][j], 0, 0, 0);
    }
    __syncthreads();
  }
  const int rbase = (lane >> 4) * 4;
  const int cbase = lane & 15;
#pragma unroll
  for (int i = 0; i < 4; ++i) {
#pragma unroll
    for (int j = 0; j < 4; ++j) {
      int col = n0 + wn * 64 + j * 16 + cbase;
      if (col < N) {
        float bv = bias[col];
#pragma unroll
        for (int r = 0; r < 4; ++r) {
          int row = m0 + wm * 64 + i * 16 + rbase + r;
          C[(size_t)row * ldc + col] = acc[i][j][r] + bv;
        }
      }
    }
  }
}

// ---------------- persistent recurrence kernel ----------------
// 96 blocks x 512 thr. type=bid>>5: 0=L0, 1=L1a, 2=L1b; nt=bid&31 -> 32 n-cols.
// Wave w: m-tile (w&3) x k-half (w>>2); each wave: 16 rows x 32 cols x 512 k.
// A-state/P via IC (relaxed agent atomics); weights in LDS; U0/b1 normally cached.
__global__ __launch_bounds__(512, 1) void rnn_persist(
    const unsigned short* __restrict__ B0c,
    const unsigned short* __restrict__ B1a,
    const unsigned short* __restrict__ B1b,
    const float* __restrict__ U0,
    const float* __restrict__ b1,
    unsigned short* __restrict__ A0x, unsigned short* __restrict__ A0y,
    unsigned short* __restrict__ A1x, unsigned short* __restrict__ A1y,
    float* __restrict__ P0, float* __restrict__ P1,
    unsigned short* __restrict__ H1bf,
    float* __restrict__ hid0, float* __restrict__ hid1,
    unsigned int* cnt) {
  __shared__ __align__(16) unsigned short Wlds[32 * 2048];   // 128 KB
  __shared__ __align__(16) float red[8 * 512];               // 16 KB

  const int bid  = blockIdx.x;          // 0..95
  const int type = bid >> 5;            // 0=L0, 1=L1a, 2=L1b
  const int nt   = bid & 31;
  const int n0   = nt << 5;             // 32 output cols
  const int tid  = threadIdx.x, lane = tid & 63, w = tid >> 6;
  const int mt = w & 3, kh = w >> 2;

  // weight slice preload (32 rows x 2048 shorts, chunk-XOR swizzled)
  const unsigned short* Wsrc = (type == 0) ? B0c : (type == 1) ? B1a : B1b;
  for (int c = tid; c < 8192; c += 512) {
    int row = c >> 8, cc = c & 255;
    bf16x8 v = *reinterpret_cast<const bf16x8*>(Wsrc + (size_t)(n0 + row) * 2048 + cc * 8);
    *reinterpret_cast<bf16x8*>(&Wlds[row * 2048 + (cc ^ (row & 7)) * 8]) = v;
  }
  __syncthreads();

  const int brow = lane & 15;
  const int kgrp = lane >> 4;           // 0..3
  const int bsw  = brow & 7;
  const size_t rowOff = (size_t)(mt * 16 + brow) * 4096;   // A row stride 4096 B
  const int colB0 = kh * 128 + kgrp * 16;                  // byte off of kc0-hi in chunk
  // epilogue geometry: thread -> (batch row em, cols c4..c4+3)
  const int em = tid >> 3;
  const int c4 = (tid & 7) << 2;
  const int n0c4 = n0 + c4;
  const int emt = em >> 4, eml = em & 15;

#define LOADC(dst, c) { \
    const char* pb_ = AprevB + rowOff + (c) * 256 + colB0; \
    dst[0] = AL64(pb_);        dst[1] = AL64(pb_ + 8); \
    dst[2] = AL64(pb_ + 2048); dst[3] = AL64(pb_ + 2056); \
    dst[4] = AL64(pb_ + 64);   dst[5] = AL64(pb_ + 72); \
    dst[6] = AL64(pb_ + 2112); dst[7] = AL64(pb_ + 2120); }

#define MFMAC(q, c) { \
    const int cb_  = (c) * 16 + kh * 8 + kgrp; \
    const int ch0_ = (cb_ ^ bsw) * 8; \
    const int ch1_ = ((cb_ + 4) ^ bsw) * 8; \
    bf16x8 ah0 = mk2(q[0], q[1]), al0 = mk2(q[2], q[3]); \
    bf16x8 ah1 = mk2(q[4], q[5]), al1 = mk2(q[6], q[7]); \
    const unsigned short* bp0_ = Wlds + brow * 2048; \
    const unsigned short* bp1_ = Wlds + (16 + brow) * 2048; \
    bf16x8 bh00 = *(const bf16x8*)(bp0_ + ch0_), bl00 = *(const bf16x8*)(bp0_ + ch0_ + 1024); \
    bf16x8 bh10 = *(const bf16x8*)(bp1_ + ch0_), bl10 = *(const bf16x8*)(bp1_ + ch0_ + 1024); \
    bf16x8 bh01 = *(const bf16x8*)(bp0_ + ch1_), bl01 = *(const bf16x8*)(bp0_ + ch1_ + 1024); \
    bf16x8 bh11 = *(const bf16x8*)(bp1_ + ch1_), bl11 = *(const bf16x8*)(bp1_ + ch1_ + 1024); \
    a00 = __builtin_amdgcn_mfma_f32_16x16x32_bf16(ah0, bh00, a00, 0, 0, 0); \
    a00 = __builtin_amdgcn_mfma_f32_16x16x32_bf16(ah0, bl00, a00, 0, 0, 0); \
    a00 = __builtin_amdgcn_mfma_f32_16x16x32_bf16(al0, bh00, a00, 0, 0, 0); \
    a01 = __builtin_amdgcn_mfma_f32_16x16x32_bf16(ah0, bh10, a01, 0, 0, 0); \
    a01 = __builtin_amdgcn_mfma_f32_16x16x32_bf16(ah0, bl10, a01, 0, 0, 0); \
    a01 = __builtin_amdgcn_mfma_f32_16x16x32_bf16(al0, bh10, a01, 0, 0, 0); \
    a10 = __builtin_amdgcn_mfma_f32_16x16x32_bf16(ah1, bh01, a10, 0, 0, 0); \
    a10 = __builtin_amdgcn_mfma_f32_16x16x32_bf16(ah1, bl01, a10, 0, 0, 0); \
    a10 = __builtin_amdgcn_mfma_f32_16x16x32_bf16(al1, bh01, a10, 0, 0, 0); \
    a11 = __builtin_amdgcn_mfma_f32_16x16x32_bf16(ah1, bh11, a11, 0, 0, 0); \
    a11 = __builtin_amdgcn_mfma_f32_16x16x32_bf16(ah1, bl11, a11, 0, 0, 0); \
    a11 = __builtin_amdgcn_mfma_f32_16x16x32_bf16(al1, bh11, a11, 0, 0, 0); }

  for (int p = 0; p < 66; ++p) {
    const int pm = p & 1;
    // ---- wait for the two phase-(p-1) producer counters this type depends on ----
    if (p > 0) {
      if (tid == 0) {
        const unsigned pm1 = (unsigned)(p - 1);
        const unsigned ia = ((type == 2) ? 66u : 0u) + pm1;     // c1 : c0
        const unsigned ib = ((type == 0) ? 66u : 132u) + pm1;   // c1 : c2
        while (__hip_atomic_load(&cnt[ia], __ATOMIC_RELAXED, __HIP_MEMORY_SCOPE_AGENT) < (unsigned)NBT)
          __builtin_amdgcn_s_sleep(1);
        while (__hip_atomic_load(&cnt[ib], __ATOMIC_RELAXED, __HIP_MEMORY_SCOPE_AGENT) < (unsigned)NBT)
          __builtin_amdgcn_s_sleep(1);
      }
      __syncthreads();
      asm volatile("" ::: "memory");
    }
    const bool active = (type == 0) ? (p < 64)
                      : (type == 1) ? (p >= 1 && p < 65)
                      : (p >= 2);
    if (active) {
      const unsigned short* Aprev = (type == 2) ? (pm ? A1y : A1x) : (pm ? A0y : A0x);
      const char* AprevB = (const char*)Aprev;

      // epilogue operand prefetch
      float4 preU = {0.f, 0.f, 0.f, 0.f}, b1v = {0.f, 0.f, 0.f, 0.f};
      u64 pq0 = 0, pq1 = 0;
      if (type == 0) {
        preU = *reinterpret_cast<const float4*>(U0 + (size_t)p * 65536 + (size_t)em * 1024 + n0c4);
      } else if (type == 2) {
        const float* Pp = pm ? P1 : P0;
        pq0 = AL64(Pp + (size_t)em * 1024 + n0c4);
        pq1 = AL64(Pp + (size_t)em * 1024 + n0c4 + 2);
        b1v = *reinterpret_cast<const float4*>(b1 + n0c4);
      }

      f32x4 a00 = {0.f,0.f,0.f,0.f}, a01 = {0.f,0.f,0.f,0.f};
      f32x4 a10 = {0.f,0.f,0.f,0.f}, a11 = {0.f,0.f,0.f,0.f};
      u64 qe[8], qo[8];
      LOADC(qe, 0); LOADC(qo, 1);
      MFMAC(qe, 0); LOADC(qe, 2);
      MFMAC(qo, 1); LOADC(qo, 3);
      MFMAC(qe, 2); LOADC(qe, 4);
      MFMAC(qo, 3); LOADC(qo, 5);
      MFMAC(qe, 4); LOADC(qe, 6);
      MFMAC(qo, 5); LOADC(qo, 7);
      MFMAC(qe, 6);
      MFMAC(qo, 7);

      // cross-(k-half) reduction in LDS
      {
        const int rr = kgrp * 4;
#pragma unroll
        for (int r = 0; r < 4; ++r) {
          red[w * 512 + (rr + r) * 32 + brow]      = a00[r] + a10[r];
          red[w * 512 + (rr + r) * 32 + 16 + brow] = a01[r] + a11[r];
        }
      }
      __syncthreads();
      {
        const int rb = emt * 512 + eml * 32 + c4;
        float v0 = red[rb]     + red[rb + 2048];
        float v1 = red[rb + 1] + red[rb + 2049];
        float v2 = red[rb + 2] + red[rb + 2050];
        float v3 = red[rb + 3] + red[rb + 2051];
        if (type == 0) {
          float h0 = tanhf(v0 + preU.x), h1 = tanhf(v1 + preU.y);
          float h2 = tanhf(v2 + preU.z), h3 = tanhf(v3 + preU.w);
          u64 lv, hv = pack4(h0, h1, h2, h3, &lv);
          unsigned short* An = pm ? A0x : A0y;
          AS64(An + (size_t)em * 2048 + n0c4, hv);
          AS64(An + (size_t)em * 2048 + 1024 + n0c4, lv);
          if (p == S_LEN - 1) {
            float4 f; f.x = h0; f.y = h1; f.z = h2; f.w = h3;
            *reinterpret_cast<float4*>(hid0 + (size_t)em * 1024 + n0c4) = f;
          }
        } else if (type == 1) {
          float* Pn = pm ? P0 : P1;
          union { u64 q; float f[2]; } ua, ub;
          ua.f[0] = v0; ua.f[1] = v1; ub.f[0] = v2; ub.f[1] = v3;
          AS64(Pn + (size_t)em * 1024 + n0c4, ua.q);
          AS64(Pn + (size_t)em * 1024 + n0c4 + 2, ub.q);
        } else {
          union { u64 q; float f[2]; } ua, ub;
          ua.q = pq0; ub.q = pq1;
          float h0 = tanhf(v0 + ua.f[0] + b1v.x), h1 = tanhf(v1 + ua.f[1] + b1v.y);
          float h2 = tanhf(v2 + ub.f[0] + b1v.z), h3 = tanhf(v3 + ub.f[1] + b1v.w);
          u64 lv, hv = pack4(h0, h1, h2, h3, &lv);
          unsigned short* An = pm ? A1x : A1y;
          AS64(An + (size_t)em * 2048 + n0c4, hv);
          AS64(An + (size_t)em * 2048 + 1024 + n0c4, lv);
          *reinterpret_cast<u64*>(H1bf + (size_t)(p - 2) * 65536 + (size_t)em * 1024 + n0c4) = hv;
          if (p == 65) {
            float4 f; f.x = h0; f.y = h1; f.z = h2; f.w = h3;
            *reinterpret_cast<float4*>(hid1 + (size_t)em * 1024 + n0c4) = f;
          }
        }
      }
    }
    // ---- arrive: all this block's stores complete, then one counter bump ----
    asm volatile("s_waitcnt vmcnt(0)" ::: "memory");
    __syncthreads();
    if (tid == 0)
      __hip_atomic_fetch_add(&cnt[type * 66 + p], 1u, __ATOMIC_RELAXED, __HIP_MEMORY_SCOPE_AGENT);
  }
#undef LOADC
#undef MFMAC
}

// ---------------- launcher ----------------

extern "C" void kernel_launch(void* const* d_in, const int* in_sizes, int n_in,
                              void* d_out, int out_size, void* d_ws, size_t ws_size,
                              hipStream_t stream) {
  (void)in_sizes; (void)n_in; (void)out_size; (void)ws_size;
  const int*   inputs = (const int*)  d_in[0];
  const float* hidden = (const float*)d_in[1];
  const float* emb    = (const float*)d_in[2];
  const float* W0     = (const float*)d_in[3];
  const float* Wh0    = (const float*)d_in[4];
  const float* b0     = (const float*)d_in[5];
  const float* W1     = (const float*)d_in[6];
  const float* Wh1    = (const float*)d_in[7];
  const float* b1     = (const float*)d_in[8];
  const float* Wd     = (const float*)d_in[9];
  const float* bd     = (const float*)d_in[10];

  // scratch inside d_out (consumed before the decoder overwrites logits)
  float*          U0  = (float*)d_out;                                       // 16MB
  unsigned short* Xbf = (unsigned short*)((char*)d_out + (size_t)16777216);  // 8MB

  // persistent scratch in d_ws
  char* ws = (char*)d_ws;
  size_t off = 0;
  auto alloc = [&](size_t bytes) { size_t p = off; off = (off + bytes + 255) & ~(size_t)255; return p; };
  unsigned short* W0bf = (unsigned short*)(ws + alloc((size_t)HID * HID * 2));
  unsigned short* Wdbf = (unsigned short*)(ws + alloc((size_t)VPAD * HID * 2));
  float*          bdp  = (float*)         (ws + alloc((size_t)VPAD * 4));
  unsigned short* B0c  = (unsigned short*)(ws + alloc((size_t)HID * 2048 * 2));
  unsigned short* B1a  = (unsigned short*)(ws + alloc((size_t)HID * 2048 * 2));
  unsigned short* B1b  = (unsigned short*)(ws + alloc((size_t)HID * 2048 * 2));
  unsigned short* H1bf = (unsigned short*)(ws + alloc((size_t)SB * HID * 2));
  unsigned short* A0x  = (unsigned short*)(ws + alloc((size_t)BATCH * 2048 * 2));
  unsigned short* A0y  = (unsigned short*)(ws + alloc((size_t)BATCH * 2048 * 2));
  unsigned short* A1x  = (unsigned short*)(ws + alloc((size_t)BATCH * 2048 * 2));
  unsigned short* A1y  = (unsigned short*)(ws + alloc((size_t)BATCH * 2048 * 2));
  float*          P0   = (float*)         (ws + alloc((size_t)BATCH * HID * 4));
  float*          P1   = (float*)         (ws + alloc((size_t)BATCH * HID * 4));
  unsigned int*   cnt  = (unsigned int*)  (ws + alloc(1024));

  float* hid0 = (float*)d_out + (size_t)SBV;            // final h0 [B,H]
  float* hid1 = hid0 + (size_t)BATCH * HID;             // final h1 [B,H]

  // prep
  prep_x <<<SB * HID / 4 / 256, 256, 0, stream>>>(inputs, emb, Xbf);
  prep_w <<<HID * HID / 256,    256, 0, stream>>>(W0, Wh0, W1, Wh1, W0bf, B0c, B1a, B1b);
  prep_wd<<<VPAD * HID / 256,   256, 0, stream>>>(Wd, bd, Wdbf, bdp);
  prep_h <<<BATCH * HID / 256,  256, 0, stream>>>(hidden, A0x, A1x, cnt);

  // U0 = X @ W0^T + b0
  gemm_bt_bias<<<dim3(HID / 128, SB / 128), 256, 0, stream>>>(
      Xbf, W0bf, b0, U0, HID, HID, HID);

  // persistent recurrence (96 blocks x 512 thr, 144KB LDS, cooperative for co-residency)
  {
    const unsigned short* cB0c = B0c; const unsigned short* cB1a = B1a;
    const unsigned short* cB1b = B1b; const float* cU0 = U0; const float* cb1 = b1;
    void* args[] = {
        (void*)&cB0c, (void*)&cB1a, (void*)&cB1b, (void*)&cU0, (void*)&cb1,
        (void*)&A0x, (void*)&A0y, (void*)&A1x, (void*)&A1y,
        (void*)&P0, (void*)&P1, (void*)&H1bf, (void*)&hid0, (void*)&hid1,
        (void*)&cnt};
    hipLaunchCooperativeKernel(reinterpret_cast<const void*>(&rnn_persist),
                               dim3(NBLK), dim3(512), args, 0, stream);
  }

  // logits = H1 @ Wd^T + bd
  gemm_bt_bias<<<dim3(VPAD / 128, SB / 128), 256, 0, stream>>>(
      H1bf, Wdbf, bdp, (float*)d_out, HID, VOCAB, VOCAB);
}